// Round 1
// baseline (4300.560 us; speedup 1.0000x reference)
//
#include <hip/hip_runtime.h>

#define FEAT 64
#define N_DATA 542080
#define N_TRUNC 40320

// Edge-scatter with atomics: out[b, dst[e], :] += w[e] * h[b, src[e], :]
// 16 threads per (edge, batch); each thread handles a float4 feature chunk.
__global__ __launch_bounds__(256) void sparse_project_atomic(
    const float* __restrict__ h,   // input base (batch b at h + b*h_bstride)
    size_t h_bstride,
    float* __restrict__ out,       // output base (batch b at out + b*out_bstride)
    size_t out_bstride,
    const int* __restrict__ src,
    const int* __restrict__ dst,
    const float* __restrict__ w,
    int n_edges)
{
    int id = blockIdx.x * blockDim.x + threadIdx.x;
    int e = id >> 4;          // 16 threads per edge
    int c = id & 15;          // float4 chunk index (16 * 4 = 64 feats)
    if (e >= n_edges) return;
    int b = blockIdx.y;

    const float* hb = h + (size_t)b * h_bstride;
    float*       ob = out + (size_t)b * out_bstride;

    int   s  = src[e];
    int   d  = dst[e];
    float ww = w[e];

    const float4 v = *reinterpret_cast<const float4*>(hb + (size_t)s * FEAT + c * 4);
    float* op = ob + (size_t)d * FEAT + c * 4;
    atomicAdd(op + 0, ww * v.x);
    atomicAdd(op + 1, ww * v.y);
    atomicAdd(op + 2, ww * v.z);
    atomicAdd(op + 3, ww * v.w);
}

extern "C" void kernel_launch(void* const* d_in, const int* in_sizes, int n_in,
                              void* d_out, int out_size, void* d_ws, size_t ws_size,
                              hipStream_t stream) {
    const float* x        = (const float*)d_in[0];   // (2, 2, 1, N_DATA, F)
    const int*   down_src = (const int*)d_in[1];
    const int*   down_dst = (const int*)d_in[2];
    const float* down_w   = (const float*)d_in[3];
    const int*   up_src   = (const int*)d_in[4];
    const int*   up_dst   = (const int*)d_in[5];
    const float* up_w     = (const float*)d_in[6];
    float* out = (float*)d_out;

    const int e_down = in_sizes[1];
    const int e_up   = in_sizes[4];

    float* h_trunc = (float*)d_ws;  // (2, N_TRUNC, F) fp32 = 20.6 MB

    const size_t trunc_elems = (size_t)2 * N_TRUNC * FEAT;
    // ws and out are poisoned 0xAA before every call — zero both.
    hipMemsetAsync(h_trunc, 0, trunc_elems * sizeof(float), stream);
    hipMemsetAsync(out, 0, (size_t)out_size * sizeof(float), stream);

    // Down: x[:, -1] (batch b at offset (2b+1)*N*F) -> h_trunc
    {
        dim3 grid((e_down * 16 + 255) / 256, 2);
        sparse_project_atomic<<<grid, 256, 0, stream>>>(
            x + (size_t)N_DATA * FEAT,            // t = T-1 = 1 slice for b = 0
            (size_t)2 * N_DATA * FEAT,            // batch stride
            h_trunc,
            (size_t)N_TRUNC * FEAT,
            down_src, down_dst, down_w, e_down);
    }
    // Up: h_trunc -> out
    {
        dim3 grid((e_up * 16 + 255) / 256, 2);
        sparse_project_atomic<<<grid, 256, 0, stream>>>(
            h_trunc,
            (size_t)N_TRUNC * FEAT,
            out,
            (size_t)N_DATA * FEAT,
            up_src, up_dst, up_w, e_up);
    }
}

// Round 2
// 1118.420 us; speedup vs baseline: 3.8452x; 3.8452x over previous
//
#include <hip/hip_runtime.h>

#define FEAT 64
#define N_DATA 542080
#define N_TRUNC 40320
#define SCAN_TILE 4096   // elements per scan block (256 threads x 16)

// ---------------- CSR build kernels ----------------

__global__ void histogram_dst(const int* __restrict__ dst, int n_edges,
                              int* __restrict__ counts) {
    int e = blockIdx.x * blockDim.x + threadIdx.x;
    if (e < n_edges) atomicAdd(&counts[dst[e]], 1);
}

__global__ void scan_block_sums(const int* __restrict__ counts, int n,
                                int* __restrict__ blockSums) {
    __shared__ int lds[256];
    int tid = threadIdx.x;
    int base = blockIdx.x * SCAN_TILE + tid * 16;
    int s = 0;
    #pragma unroll
    for (int i = 0; i < 16; ++i) {
        int idx = base + i;
        s += (idx < n) ? counts[idx] : 0;
    }
    lds[tid] = s;
    __syncthreads();
    for (int off = 128; off > 0; off >>= 1) {
        if (tid < off) lds[tid] += lds[tid + off];
        __syncthreads();
    }
    if (tid == 0) blockSums[blockIdx.x] = lds[0];
}

__global__ void scan_exclusive_blocksums(int* __restrict__ blockSums, int nblocks) {
    if (blockIdx.x == 0 && threadIdx.x == 0) {
        int acc = 0;
        for (int i = 0; i < nblocks; ++i) {
            int v = blockSums[i];
            blockSums[i] = acc;
            acc += v;
        }
    }
}

__global__ void scan_write_offsets(const int* __restrict__ counts, int n,
                                   const int* __restrict__ blockSums,
                                   int* __restrict__ offsets, int total_edges) {
    __shared__ int lds[256];
    int tid = threadIdx.x;
    int base = blockIdx.x * SCAN_TILE + tid * 16;
    int local[16];
    int s = 0;
    #pragma unroll
    for (int i = 0; i < 16; ++i) {
        int idx = base + i;
        int v = (idx < n) ? counts[idx] : 0;
        local[i] = s;           // exclusive within thread
        s += v;
    }
    lds[tid] = s;
    __syncthreads();
    // Hillis-Steele inclusive scan across 256 threads
    for (int off = 1; off < 256; off <<= 1) {
        int v = (tid >= off) ? lds[tid - off] : 0;
        __syncthreads();
        if (tid >= off) lds[tid] += v;
        __syncthreads();
    }
    int threadOffset = (tid == 0) ? 0 : lds[tid - 1];
    int blockOffset = blockSums[blockIdx.x];
    #pragma unroll
    for (int i = 0; i < 16; ++i) {
        int idx = base + i;
        if (idx < n) offsets[idx] = blockOffset + threadOffset + local[i];
    }
    if (blockIdx.x == 0 && tid == 0) offsets[n] = total_edges;
}

__global__ void build_csr(const int* __restrict__ src, const int* __restrict__ dst,
                          const float* __restrict__ w, int n_edges,
                          const int* __restrict__ offsets, int* __restrict__ cursor,
                          int2* __restrict__ csr_pair) {
    int e = blockIdx.x * blockDim.x + threadIdx.x;
    if (e >= n_edges) return;
    int d = dst[e];
    int pos = offsets[d] + atomicAdd(&cursor[d], 1);
    int2 p;
    p.x = src[e];
    p.y = __float_as_int(w[e]);
    csr_pair[pos] = p;
}

// ---------------- Gather kernel ----------------
// 16 threads per output row; each thread owns one float4 feature chunk and
// accumulates BOTH batches in registers. One streaming store per (row,batch).
__global__ __launch_bounds__(256) void sparse_gather(
    const float* __restrict__ h, size_t h_bstride,
    float* __restrict__ out, size_t out_bstride,
    const int* __restrict__ offsets,
    const int2* __restrict__ csr_pair,
    int n_out)
{
    int id = blockIdx.x * blockDim.x + threadIdx.x;
    int d = id >> 4;
    int c = (id & 15) * 4;
    if (d >= n_out) return;

    int beg = offsets[d];
    int end = offsets[d + 1];

    float4 acc0 = make_float4(0.f, 0.f, 0.f, 0.f);
    float4 acc1 = make_float4(0.f, 0.f, 0.f, 0.f);

    for (int p = beg; p < end; ++p) {
        int2 pr = csr_pair[p];
        int   s  = pr.x;
        float ww = __int_as_float(pr.y);
        const float* row0 = h + (size_t)s * FEAT + c;
        const float* row1 = row0 + h_bstride;
        float4 v0 = *reinterpret_cast<const float4*>(row0);
        float4 v1 = *reinterpret_cast<const float4*>(row1);
        acc0.x += ww * v0.x; acc0.y += ww * v0.y;
        acc0.z += ww * v0.z; acc0.w += ww * v0.w;
        acc1.x += ww * v1.x; acc1.y += ww * v1.y;
        acc1.z += ww * v1.z; acc1.w += ww * v1.w;
    }
    float* o0 = out + (size_t)d * FEAT + c;
    *reinterpret_cast<float4*>(o0) = acc0;
    *reinterpret_cast<float4*>(o0 + out_bstride) = acc1;
}

// ---------------- Fallback atomic kernel (ws too small) ----------------
__global__ __launch_bounds__(256) void sparse_project_atomic(
    const float* __restrict__ h, size_t h_bstride,
    float* __restrict__ out, size_t out_bstride,
    const int* __restrict__ src, const int* __restrict__ dst,
    const float* __restrict__ w, int n_edges)
{
    int id = blockIdx.x * blockDim.x + threadIdx.x;
    int e = id >> 4;
    int c = (id & 15) * 4;
    if (e >= n_edges) return;
    int b = blockIdx.y;
    const float* hb = h + (size_t)b * h_bstride;
    float*       ob = out + (size_t)b * out_bstride;
    int   s  = src[e];
    int   d  = dst[e];
    float ww = w[e];
    const float4 v = *reinterpret_cast<const float4*>(hb + (size_t)s * FEAT + c);
    float* op = ob + (size_t)d * FEAT + c;
    atomicAdd(op + 0, ww * v.x);
    atomicAdd(op + 1, ww * v.y);
    atomicAdd(op + 2, ww * v.z);
    atomicAdd(op + 3, ww * v.w);
}

static inline size_t align16(size_t v) { return (v + 15) & ~(size_t)15; }

extern "C" void kernel_launch(void* const* d_in, const int* in_sizes, int n_in,
                              void* d_out, int out_size, void* d_ws, size_t ws_size,
                              hipStream_t stream) {
    const float* x        = (const float*)d_in[0];   // (2, 2, 1, N_DATA, F)
    const int*   down_src = (const int*)d_in[1];
    const int*   down_dst = (const int*)d_in[2];
    const float* down_w   = (const float*)d_in[3];
    const int*   up_src   = (const int*)d_in[4];
    const int*   up_dst   = (const int*)d_in[5];
    const float* up_w     = (const float*)d_in[6];
    float* out = (float*)d_out;

    const int e_down = in_sizes[1];
    const int e_up   = in_sizes[4];

    // x[:, -1] slice: batch b lives at x + (2b+1)*N_DATA*FEAT
    const float* x_last = x + (size_t)N_DATA * FEAT;
    const size_t x_bstride = (size_t)2 * N_DATA * FEAT;

    // ---- workspace layout ----
    char* ws = (char*)d_ws;
    size_t off = 0;
    float* h_trunc   = (float*)(ws + off); off += align16((size_t)2 * N_TRUNC * FEAT * 4);
    int*   up_off    = (int*)(ws + off);   off += align16(((size_t)N_DATA + 1) * 4);
    int*   down_off  = (int*)(ws + off);   off += align16(((size_t)N_TRUNC + 1) * 4);
    int*   up_cur    = (int*)(ws + off);   off += align16((size_t)N_DATA * 4);
    int*   down_cur  = (int*)(ws + off);   off += align16((size_t)N_TRUNC * 4);
    int2*  up_csr    = (int2*)(ws + off);  off += align16((size_t)e_up * 8);
    int2*  down_csr  = (int2*)(ws + off);  off += align16((size_t)e_down * 8);
    int*   blockSums = (int*)(ws + off);   off += align16(1024);
    const size_t needed = off;

    if (ws_size < needed) {
        // Fallback: round-1 atomic path (needs only h_trunc)
        hipMemsetAsync(h_trunc, 0, (size_t)2 * N_TRUNC * FEAT * 4, stream);
        hipMemsetAsync(out, 0, (size_t)out_size * sizeof(float), stream);
        dim3 g1((e_down * 16 + 255) / 256, 2);
        sparse_project_atomic<<<g1, 256, 0, stream>>>(
            x_last, x_bstride, h_trunc, (size_t)N_TRUNC * FEAT,
            down_src, down_dst, down_w, e_down);
        dim3 g2((e_up * 16 + 255) / 256, 2);
        sparse_project_atomic<<<g2, 256, 0, stream>>>(
            h_trunc, (size_t)N_TRUNC * FEAT, out, (size_t)N_DATA * FEAT,
            up_src, up_dst, up_w, e_up);
        return;
    }

    const int nblk_down = (N_TRUNC + SCAN_TILE - 1) / SCAN_TILE;   // 10
    const int nblk_up   = (N_DATA  + SCAN_TILE - 1) / SCAN_TILE;   // 133

    // ---- build CSR for down phase (counts in down_cur, then reused as cursor) ----
    hipMemsetAsync(down_cur, 0, (size_t)N_TRUNC * 4, stream);
    histogram_dst<<<(e_down + 255) / 256, 256, 0, stream>>>(down_dst, e_down, down_cur);
    scan_block_sums<<<nblk_down, 256, 0, stream>>>(down_cur, N_TRUNC, blockSums);
    scan_exclusive_blocksums<<<1, 64, 0, stream>>>(blockSums, nblk_down);
    scan_write_offsets<<<nblk_down, 256, 0, stream>>>(down_cur, N_TRUNC, blockSums, down_off, e_down);
    hipMemsetAsync(down_cur, 0, (size_t)N_TRUNC * 4, stream);
    build_csr<<<(e_down + 255) / 256, 256, 0, stream>>>(
        down_src, down_dst, down_w, e_down, down_off, down_cur, down_csr);

    // ---- build CSR for up phase ----
    hipMemsetAsync(up_cur, 0, (size_t)N_DATA * 4, stream);
    histogram_dst<<<(e_up + 255) / 256, 256, 0, stream>>>(up_dst, e_up, up_cur);
    scan_block_sums<<<nblk_up, 256, 0, stream>>>(up_cur, N_DATA, blockSums);
    scan_exclusive_blocksums<<<1, 64, 0, stream>>>(blockSums, nblk_up);
    scan_write_offsets<<<nblk_up, 256, 0, stream>>>(up_cur, N_DATA, blockSums, up_off, e_up);
    hipMemsetAsync(up_cur, 0, (size_t)N_DATA * 4, stream);
    build_csr<<<(e_up + 255) / 256, 256, 0, stream>>>(
        up_src, up_dst, up_w, e_up, up_off, up_cur, up_csr);

    // ---- down gather: x[:, -1] -> h_trunc (both batches per thread) ----
    {
        int threads = N_TRUNC * 16;
        sparse_gather<<<(threads + 255) / 256, 256, 0, stream>>>(
            x_last, x_bstride,
            h_trunc, (size_t)N_TRUNC * FEAT,
            down_off, down_csr, N_TRUNC);
    }
    // ---- up gather: h_trunc -> out ----
    {
        int threads = N_DATA * 16;
        sparse_gather<<<(threads + 255) / 256, 256, 0, stream>>>(
            h_trunc, (size_t)N_TRUNC * FEAT,
            out, (size_t)N_DATA * FEAT,
            up_off, up_csr, N_DATA);
    }
}